// Round 5
// baseline (616.985 us; speedup 1.0000x reference)
//
#include <hip/hip_runtime.h>
#include <hip/hip_bf16.h>
#include <stdint.h>

#define NPTS   1000000
#define NTILES (NPTS / 64)        // 15625 exactly
#define HH 1024
#define WW 1024
#define MAP_BYTES (4u * 1024u * 1024u * 4u)   // 4*1024*1024 ints = 16 MB

typedef __attribute__((ext_vector_type(8))) __bf16 bf16x8;
typedef __attribute__((ext_vector_type(4))) float  f32x4;
typedef __attribute__((ext_vector_type(4))) unsigned int u32x4;

__global__ void scatter_idx(const int* __restrict__ idx, int* __restrict__ map, int n) {
    int i = blockIdx.x * 256 + threadIdx.x;
    if (i < n) {
        int b = idx[3 * i], y = idx[3 * i + 1], x = idx[3 * i + 2];
        map[(b << 20) | (y << 10) | x] = i;
    }
}

// Repack W[o][k][n] (fp32, o=ky*3+kx) into bf16 MFMA B-fragment chunks:
// elem dst = o*4096 + ((kb*4+nb)*64 + lane)*8 + j, lane=(n&15)+16*((k&31)>>3), j=k&7
__global__ void pack_weight(const float* __restrict__ w, unsigned short* __restrict__ wb) {
    int t = blockIdx.x * 256 + threadIdx.x;
    if (t < 9 * 64 * 64) {
        int o = t >> 12, rem = t & 4095, k = rem >> 6, n = rem & 63;
        int kb = k >> 5, nb = n >> 4;
        int lane = (n & 15) + 16 * ((k >> 3) & 3);
        int j = k & 7;
        int dst = o * 4096 + (((kb << 2) + nb) * 64 + lane) * 8 + j;
        __bf16 h = (__bf16)w[t];
        wb[dst] = __builtin_bit_cast(unsigned short, h);
    }
}

__global__ __launch_bounds__(256) void spconv_mfma(
    const float* __restrict__ feat, const unsigned short* __restrict__ wb,
    const float* __restrict__ bias, const int* __restrict__ idx,
    const int* __restrict__ map, float* __restrict__ out)
{
    __shared__ __align__(16) unsigned short wl[2][4096];   // 2 x 8KB W double-buffer

    const int tid  = threadIdx.x;
    const int lane = tid & 63;
    const int l15  = lane & 15;
    const int koct = lane >> 4;           // 0..3
    const int wid  = tid >> 6;
    const int tile = blockIdx.x * 4 + wid;
    const bool valid = (tile < NTILES);

    const u32x4* __restrict__ wsrc = (const u32x4*)wb;

    // ---- prologue: stage W[o=0] into buffer 0 (all threads) ----
    {
        u32x4 v0 = wsrc[tid];
        u32x4 v1 = wsrc[tid + 256];
        *(u32x4*)&wl[0][(size_t)tid * 8]        = v0;
        *(u32x4*)&wl[0][(size_t)(tid + 256) * 8] = v1;
    }

    // per-point coords (lane l owns point tile*64+l)
    int b_ = 0, y_ = 0, x_ = 0;
    if (valid) {
        int p = tile * 64 + lane;
        b_ = idx[3 * p];
        y_ = idx[3 * p + 1];
        x_ = idx[3 * p + 2];
    }

    float biasr[4];
#pragma unroll
    for (int nb = 0; nb < 4; ++nb) biasr[nb] = bias[nb * 16 + l15];

    f32x4 acc[4][4];
#pragma unroll
    for (int mb = 0; mb < 4; ++mb)
#pragma unroll
        for (int nb = 0; nb < 4; ++nb) acc[mb][nb] = (f32x4){0.f, 0.f, 0.f, 0.f};

    __syncthreads();

    int cur = 0;
#pragma unroll
    for (int o = 0; o < 9; ++o) {
        // T14: issue next-offset W loads early, write to LDS after compute
        u32x4 nv0, nv1;
        if (o < 8) {
            nv0 = wsrc[(o + 1) * 512 + tid];
            nv1 = wsrc[(o + 1) * 512 + tid + 256];
        }

        if (valid) {
            const int dy = o / 3 - 1, dx = o % 3 - 1;
            int ny = y_ + dy, nx = x_ + dx;
            int nmap = -1;
            if (ny >= 0 && ny < HH && nx >= 0 && nx < WW)
                nmap = map[(b_ << 20) | (ny << 10) | nx];

            // gather A fragments straight to registers (bf16-converted)
            bf16x8 a[4][2];
#pragma unroll
            for (int mb = 0; mb < 4; ++mb) {
                int r = __shfl(nmap, mb * 16 + l15);
                const float* fr = feat + (long long)(r < 0 ? 0 : r) * 64 + koct * 8;
                f32x4 f0 = {0.f,0.f,0.f,0.f}, f1 = f0, f2 = f0, f3 = f0;
                if (r >= 0) {
                    f0 = *(const f32x4*)(fr);
                    f1 = *(const f32x4*)(fr + 4);
                    f2 = *(const f32x4*)(fr + 32);
                    f3 = *(const f32x4*)(fr + 36);
                }
                bf16x8 a0, a1;
#pragma unroll
                for (int j = 0; j < 4; ++j) {
                    a0[j]     = (__bf16)f0[j];
                    a0[j + 4] = (__bf16)f1[j];
                    a1[j]     = (__bf16)f2[j];
                    a1[j + 4] = (__bf16)f3[j];
                }
                a[mb][0] = a0;
                a[mb][1] = a1;
            }

            // GEMM: acc += A(64x64) * W[o](64x64)
#pragma unroll
            for (int kb = 0; kb < 2; ++kb)
#pragma unroll
                for (int nb = 0; nb < 4; ++nb) {
                    bf16x8 bfrag = *(const bf16x8*)&wl[cur][(size_t)(((kb << 2) + nb) * 64 + lane) * 8];
#pragma unroll
                    for (int mb = 0; mb < 4; ++mb)
                        acc[mb][nb] = __builtin_amdgcn_mfma_f32_16x16x32_bf16(
                            a[mb][kb], bfrag, acc[mb][nb], 0, 0, 0);
                }
        }

        if (o < 8) {
            *(u32x4*)&wl[cur ^ 1][(size_t)tid * 8]         = nv0;
            *(u32x4*)&wl[cur ^ 1][(size_t)(tid + 256) * 8] = nv1;
            __syncthreads();
            cur ^= 1;
        }
    }

    // epilogue: bias + fp32 store (output buffer is float32!)
    if (valid) {
        long long base = (long long)tile * 64 * 64;
#pragma unroll
        for (int mb = 0; mb < 4; ++mb)
#pragma unroll
            for (int nb = 0; nb < 4; ++nb)
#pragma unroll
                for (int r = 0; r < 4; ++r) {
                    int row = mb * 16 + koct * 4 + r;
                    int col = nb * 16 + l15;
                    out[base + row * 64 + col] = acc[mb][nb][r] + biasr[nb];
                }
    }
}

extern "C" void kernel_launch(void* const* d_in, const int* in_sizes, int n_in,
                              void* d_out, int out_size, void* d_ws, size_t ws_size,
                              hipStream_t stream) {
    const float* feat = (const float*)d_in[0];   // (N, 64) fp32
    const float* w    = (const float*)d_in[1];   // (3,3,64,64) fp32
    const float* bias = (const float*)d_in[2];   // (64,) fp32
    const int*   idx  = (const int*)d_in[3];     // (N, 3) int32

    float*          out = (float*)d_out;               // (N, 64) fp32
    int*            map = (int*)d_ws;                  // 16 MB idx_map
    unsigned short* wb  = (unsigned short*)((char*)d_ws + MAP_BYTES); // 73728 B packed W

    hipMemsetAsync(d_ws, 0xFF, MAP_BYTES, stream);     // idx_map = -1
    scatter_idx<<<(NPTS + 255) / 256, 256, 0, stream>>>(idx, map, NPTS);
    pack_weight<<<(9 * 64 * 64 + 255) / 256, 256, 0, stream>>>(w, wb);
    spconv_mfma<<<(NTILES + 3) / 4, 256, 0, stream>>>(feat, wb, bias, idx, map, out);
}